// Round 14
// baseline (172.354 us; speedup 1.0000x reference)
//
#include <hip/hip_runtime.h>
#include <stdint.h>
#include <stddef.h>

#define B_ 4
#define S_ 2048
#define D_ 256
#define H_ 4
#define DH_ 64
#define NTT 64
#define SC_LOG2E 0.18033688011112042f  // (1/8) * log2(e)

typedef __attribute__((ext_vector_type(8))) short short8;
typedef __attribute__((ext_vector_type(4))) short short4v;
typedef __attribute__((ext_vector_type(4))) float f32x4;
typedef unsigned int uint;

__device__ __forceinline__ short bf16_rne(float f) {
  union { float f; uint32_t u; } c; c.f = f;
  uint32_t u = c.u + 0x7FFFu + ((c.u >> 16) & 1u);
  return (short)(u >> 16);
}

__device__ __forceinline__ f32x4 mfma16(short8 a, short8 b, f32x4 c) {
  return __builtin_amdgcn_mfma_f32_16x16x32_bf16(a, b, c, 0, 0, 0);
}

__device__ __forceinline__ void gl_lds16(const short* g, short* l) {
  __builtin_amdgcn_global_load_lds(
      (const __attribute__((address_space(1))) unsigned int*)g,
      (__attribute__((address_space(3))) unsigned int*)l, 16, 0, 0);
}

// ---------------- mask dtype detect: 1 = int32, 0 = byte/bool ----------------
__global__ void detect_kernel(const unsigned int* __restrict__ m, int* __restrict__ flag) {
  __shared__ int isbool;
  if (threadIdx.x == 0) isbool = 0;
  __syncthreads();
#pragma unroll
  for (int i = 0; i < 4; ++i) {
    unsigned int d = m[threadIdx.x + i * 256];
    if (d & 0xFFFFFFFEu) isbool = 1;
  }
  __syncthreads();
  if (threadIdx.x == 0) *flag = isbool ? 0 : 1;
}

// ---------------- fused: bit-pack mask (wgs 0..2047) + weight prep (wgs 2048..2367) ----------------
__global__ __launch_bounds__(256) void prep_pack(
    const unsigned char* __restrict__ maskB, const int* __restrict__ flagp,
    uint* __restrict__ mbits,
    const float* __restrict__ Wq, const float* __restrict__ Wk, const float* __restrict__ Wv,
    short* __restrict__ WqT, short* __restrict__ WkT, short* __restrict__ WvT) {
  const int bx = blockIdx.x;
  if (bx < 2048) {
    int tid = bx * 256 + threadIdx.x;  // 524288 dwords total
    uint w = 0;
    if (*flagp) {  // int32 mask
      const uint4* p = (const uint4*)((const uint*)maskB + (size_t)tid * 32);
#pragma unroll
      for (int i = 0; i < 8; ++i) {
        uint4 d = p[i];
        w |= (d.x ? 1u : 0u) << (i * 4);
        w |= (d.y ? 1u : 0u) << (i * 4 + 1);
        w |= (d.z ? 1u : 0u) << (i * 4 + 2);
        w |= (d.w ? 1u : 0u) << (i * 4 + 3);
      }
    } else {  // byte mask
      const uint4* p = (const uint4*)(maskB + (size_t)tid * 32);
#pragma unroll
      for (int i = 0; i < 2; ++i) {
        uint4 d = p[i];
        const uint* dw = (const uint*)&d;
#pragma unroll
        for (int j = 0; j < 4; ++j) {
          uint x = dw[j];
          int base = i * 16 + j * 4;
          w |= ((x & 0x000000FFu) ? 1u : 0u) << (base);
          w |= ((x & 0x0000FF00u) ? 1u : 0u) << (base + 1);
          w |= ((x & 0x00FF0000u) ? 1u : 0u) << (base + 2);
          w |= ((x & 0xFF000000u) ? 1u : 0u) << (base + 3);
        }
      }
    }
    mbits[tid] = w;
  } else {
    int tid = (bx - 2048) * 256 + threadIdx.x;  // 0..81919
    if (tid < 65536) {
      int n = tid >> 8, d = tid & 255;
      int hh = n >> 6, e = n & 63;
      WqT[tid] = bf16_rne(Wq[((size_t)hh * D_ + d) * DH_ + e] * SC_LOG2E);
      WkT[tid] = bf16_rne(Wk[((size_t)hh * D_ + d) * DH_ + e]);
    } else {
      int t2 = tid - 65536;
      int e = t2 >> 8, d = t2 & 255;
      WvT[t2] = bf16_rne(Wv[(size_t)d * DH_ + e]);
    }
  }
}

// ---------------- merged projections: y 0-3 = q, 4-7 = k, 8 = v ----------------
__global__ __launch_bounds__(256) void proj_all(
    const float* __restrict__ q, const float* __restrict__ k, const float* __restrict__ v,
    const short* __restrict__ WqT, const short* __restrict__ WkT, const short* __restrict__ WvT,
    const float* __restrict__ bq, const float* __restrict__ bk, const float* __restrict__ bv,
    short* __restrict__ qh, short* __restrict__ kh, short* __restrict__ vT) {
  const int yy = blockIdx.y;
  const float* X; const short* WT; const float* bias; short* outp;
  int vmode, n0; float bscale;
  if (yy < 4)      { X = q; WT = WqT; bias = bq; outp = qh; vmode = 0; bscale = SC_LOG2E; n0 = yy * 64; }
  else if (yy < 8) { X = k; WT = WkT; bias = bk; outp = kh; vmode = 0; bscale = 1.0f; n0 = (yy - 4) * 64; }
  else             { X = v; WT = WvT; bias = bv; outp = vT; vmode = 1; bscale = 1.0f; n0 = 0; }

  const int b = blockIdx.z;
  const int s0 = blockIdx.x * 64;
  const int tid = threadIdx.x;
  const int wave = tid >> 6, lane = tid & 63;
  const int lr = lane & 15, lg = lane >> 4;

  const int arowi = s0 + wave * 16 + lr;
  const float* xr = X + ((size_t)b * S_ + arowi) * D_;

  f32x4 zero4 = {0.f, 0.f, 0.f, 0.f};
  f32x4 acc[4];
#pragma unroll
  for (int ct = 0; ct < 4; ++ct) acc[ct] = zero4;

#pragma unroll
  for (int c = 0; c < 8; ++c) {
    const int k0 = c * 32 + lg * 8;
    f32x4 x0 = *(const f32x4*)(xr + k0);
    f32x4 x1 = *(const f32x4*)(xr + k0 + 4);
    short8 a;
#pragma unroll
    for (int jj = 0; jj < 4; ++jj) { a[jj] = bf16_rne(x0[jj]); a[4 + jj] = bf16_rne(x1[jj]); }
#pragma unroll
    for (int ct = 0; ct < 4; ++ct) {
      short8 bw = *(const short8*)(WT + (size_t)(n0 + ct * 16 + lr) * D_ + k0);
      acc[ct] = mfma16(a, bw, acc[ct]);
    }
  }

  if (vmode == 0) {
#pragma unroll
    for (int ct = 0; ct < 4; ++ct) {
      int n = n0 + ct * 16 + lr;
      float bb = bias[n] * bscale;
      int hh = n >> 6, e = n & 63;
#pragma unroll
      for (int r = 0; r < 4; ++r) {
        int srow = s0 + wave * 16 + lg * 4 + r;
        outp[(((size_t)b * H_ + hh) * S_ + srow) * DH_ + e] = bf16_rne(acc[ct][r] + bb);
      }
    }
  } else {
#pragma unroll
    for (int ct = 0; ct < 4; ++ct) {
      int n = n0 + ct * 16 + lr;
      float bb = bias[n];
      int s4 = s0 + wave * 16 + lg * 4;
      short4v pk;
#pragma unroll
      for (int r = 0; r < 4; ++r) pk[r] = bf16_rne(acc[ct][r] + bb);
      *(short4v*)(outp + ((size_t)b * DH_ + n) * S_ + s4) = pk;
    }
  }
}

// ---------------- staging helpers (NTT=64 tiles, inverse-swizzled source) ----------------
__device__ __forceinline__ void stageK64(const short* Ksrc, short* dst, int wq, int lane) {
#pragma unroll
  for (int i = 0; i < 2; ++i) {
    int ub = i * 256 + wq * 64;
    int u = ub + lane;
    int row = u >> 3, c = (u ^ row) & 7;
    gl_lds16(Ksrc + (size_t)row * 64 + c * 8, dst + (size_t)ub * 8);
  }
}

__device__ __forceinline__ void stageV64(const short* Vb, int t0, short* dst, int wq, int lane) {
#pragma unroll
  for (int i = 0; i < 2; ++i) {
    int ub = i * 256 + wq * 64;
    int u = ub + lane;
    int er = u >> 3, c = (u ^ er) & 7;
    gl_lds16(Vb + (size_t)er * S_ + t0 + c * 8, dst + (size_t)ub * 8);
  }
}

// ---------------- fused masked attention (R10 structure, single barrier per tile) ----------------
// grid 512 (XCD-swizzled), 512 thr. Waves 0-3: t in [0,1024); waves 4-7: t in [1024,2048).
// Per tile: {mask; stage(t+1) into buf[cur^1] (overwrites buffer read at t-1, fenced by the
// PREVIOUS end-of-tile barrier); compute(t) from buf[cur]; vmcnt(N); barrier}. One barrier/tile.
// N: pass1=0 (only stage outstanding), pass2=4 (attn stores keep flying). Stores never drained.
__global__ __launch_bounds__(512, 4) void attn_kernel(
    const short* __restrict__ qh, const short* __restrict__ kh,
    const short* __restrict__ vT, const uint* __restrict__ mbits,
    float* __restrict__ attn, float* __restrict__ heads) {
  __shared__ __align__(16) short Kt[2][2][4096];  // [half][dbuf] 32 KB
  __shared__ __align__(16) short Vt[2][2][4096];  // [half][dbuf] 32 KB
  __shared__ __align__(16) short Pt[8][1024];     // per-wave P slab, 16 KB (aliased: fsum, ocomb)

  const int flat = blockIdx.x;
  const int xcd = flat & 7;
  const int pos = flat >> 3;              // 0..63
  const int bh_i = xcd * 2 + (pos >> 5);  // 2 (b,h) per XCD
  const int q0 = (pos & 31) * 64;
  const int b = bh_i >> 2, h = bh_i & 3;

  const int tid = threadIdx.x;
  const int wave = tid >> 6, lane = tid & 63;
  const int half = wave >> 2, wq = wave & 3;
  const int lr = lane & 15, lg = lane >> 4;
  const int tbase = half * (S_ / 2);

  const size_t bh = (size_t)b * H_ + h;
  const short* Qb = qh + bh * S_ * DH_;
  const short* Kb = kh + bh * S_ * DH_;
  const short* Vb = vT + (size_t)b * DH_ * S_;

  const int qrow = q0 + wq * 16 + lr;
  const uint* mrow = mbits + ((size_t)b * S_ + qrow) * (S_ / 32);
  float* arow = attn + (bh * S_ + qrow) * S_;

  const short8 aq0 = *(const short8*)(Qb + (size_t)qrow * DH_ + lg * 8);
  const short8 aq1 = *(const short8*)(Qb + (size_t)qrow * DH_ + 32 + lg * 8);

  short* pw = &Pt[wave][0];

  // -------- pass 1: partial row sums over this wave's t-half --------
  float rsum = 0.f;
  stageK64(Kb + (size_t)tbase * DH_, Kt[half][0], wq, lane);
  asm volatile("s_waitcnt vmcnt(0)" ::: "memory");
  __builtin_amdgcn_s_barrier();
  int cur = 0;
  for (int tt = 0; tt < 16; ++tt) {
    const int t0 = tbase + tt * NTT;
    uint2 mv = *(const uint2*)(mrow + (t0 >> 5));  // issued before stage: compiler waits
                                                   // vmcnt(2) for it, stage stays in flight
    if (tt + 1 < 16)
      stageK64(Kb + (size_t)(t0 + NTT) * DH_, Kt[half][cur ^ 1], wq, lane);
    __builtin_amdgcn_s_setprio(1);
    const short* kt = Kt[half][cur];
#pragma unroll
    for (int j = 0; j < 4; ++j) {
      int row = j * 16 + lr;
      short8 bk0 = *(const short8*)(kt + row * 64 + (((lg) ^ row) & 7) * 8);
      short8 bk1 = *(const short8*)(kt + row * 64 + (((lg + 4) ^ row) & 7) * 8);
      f32x4 acc = {0.f, 0.f, 0.f, 0.f};
      acc = mfma16(bk0, aq0, acc);
      acc = mfma16(bk1, aq1, acc);
      uint mw = (j < 2) ? mv.x : mv.y;
#pragma unroll
      for (int r = 0; r < 4; ++r) {
        int sh = (j & 1) * 16 + lg * 4 + r;
        float p = ((mw >> sh) & 1u) ? 0.f : __builtin_exp2f(acc[r]);
        rsum += p;
      }
    }
    __builtin_amdgcn_s_setprio(0);
    asm volatile("s_waitcnt vmcnt(0)" ::: "memory");  // stage(tt+1) retired (no-op on last)
    __builtin_amdgcn_s_barrier();  // single barrier: buf[cur^1] ready AND buf[cur] free
    cur ^= 1;
  }
  rsum += __shfl_xor(rsum, 16);
  rsum += __shfl_xor(rsum, 32);
  // combine the two t-halves through LDS (fsum aliased onto Pt)
  float* fsum = (float*)&Pt[0][0];  // [8][16]
  if (lane < 16) fsum[wave * 16 + lr] = rsum;
  __syncthreads();
  const float rinv = 1.0f / (fsum[wq * 16 + lr] + fsum[(wq + 4) * 16 + lr]);

  // -------- pass 2: recompute, write attn (float4), PV partials --------
  f32x4 o[4];
#pragma unroll
  for (int ct = 0; ct < 4; ++ct) o[ct] = (f32x4){0.f, 0.f, 0.f, 0.f};

  stageK64(Kb + (size_t)tbase * DH_, Kt[half][0], wq, lane);
  stageV64(Vb, tbase, Vt[half][0], wq, lane);
  asm volatile("s_waitcnt vmcnt(0)" ::: "memory");
  __syncthreads();
  cur = 0;
  for (int tt = 0; tt < 16; ++tt) {
    const int t0 = tbase + tt * NTT;
    uint2 mv = *(const uint2*)(mrow + (t0 >> 5));
    if (tt + 1 < 16) {
      stageK64(Kb + (size_t)(t0 + NTT) * DH_, Kt[half][cur ^ 1], wq, lane);
      stageV64(Vb, t0 + NTT, Vt[half][cur ^ 1], wq, lane);
    }
    __builtin_amdgcn_s_setprio(1);
    const short* kt = Kt[half][cur];
    const short* vt = Vt[half][cur];
#pragma unroll
    for (int j = 0; j < 4; ++j) {
      int row = j * 16 + lr;
      short8 bk0 = *(const short8*)(kt + row * 64 + (((lg) ^ row) & 7) * 8);
      short8 bk1 = *(const short8*)(kt + row * 64 + (((lg + 4) ^ row) & 7) * 8);
      f32x4 acc = {0.f, 0.f, 0.f, 0.f};
      acc = mfma16(bk0, aq0, acc);
      acc = mfma16(bk1, aq1, acc);
      uint mw = (j < 2) ? mv.x : mv.y;
      f32x4 pst;
      short4v pk;
#pragma unroll
      for (int r = 0; r < 4; ++r) {
        int sh = (j & 1) * 16 + lg * 4 + r;
        float p = ((mw >> sh) & 1u) ? 0.f : __builtin_exp2f(acc[r]) * rinv;
        pst[r] = p;
        pk[r] = bf16_rne(p);
      }
      *(f32x4*)(arow + t0 + j * 16 + lg * 4) = pst;
      *(short4v*)(pw + lr * 64 + (((2 * j + (lg >> 1)) ^ lr) & 7) * 8 + (lg & 1) * 4) = pk;
    }
    // PV: o[e][q] += V^T[e][t] * P[q][t]; apf is ct-invariant -> hoisted
    short8 apf[2];
#pragma unroll
    for (int kc = 0; kc < 2; ++kc)
      apf[kc] = *(const short8*)(pw + lr * 64 + (((4 * kc + lg) ^ lr) & 7) * 8);
#pragma unroll
    for (int ct = 0; ct < 4; ++ct) {
      int er = ct * 16 + lr;
#pragma unroll
      for (int kc = 0; kc < 2; ++kc) {
        short8 bvf = *(const short8*)(vt + er * 64 + (((4 * kc + lg) ^ er) & 7) * 8);
        o[ct] = mfma16(bvf, apf[kc], o[ct]);
      }
    }
    __builtin_amdgcn_s_setprio(0);
    asm volatile("s_waitcnt vmcnt(4)" ::: "memory");  // stage(tt+1) retired; 4 stores fly
    __builtin_amdgcn_s_barrier();  // single barrier per tile
    cur ^= 1;
  }

  // -------- combine o partials across the two t-halves (ocomb aliased onto Pt) --------
  // Last-tile barrier above guarantees all waves finished reading their Pt slabs.
  float* ocomb = (float*)&Pt[0][0];  // [4][16][64] floats = 16 KB
  if (half == 1) {
#pragma unroll
    for (int ct = 0; ct < 4; ++ct)
      *(f32x4*)(ocomb + wq * 1024 + lr * 64 + ct * 16 + lg * 4) = o[ct];
  }
  __syncthreads();
  if (half == 0) {
#pragma unroll
    for (int ct = 0; ct < 4; ++ct) {
      f32x4 t = *(const f32x4*)(ocomb + wq * 1024 + lr * 64 + ct * 16 + lg * 4);
      f32x4 s = o[ct];
      s[0] += t[0]; s[1] += t[1]; s[2] += t[2]; s[3] += t[3];
      *(f32x4*)(heads + (bh * S_ + qrow) * DH_ + ct * 16 + lg * 4) = s;
    }
  }
}

// ---------------- mean over heads + final projection ----------------
__global__ __launch_bounds__(256) void final_kernel(
    const float* __restrict__ heads, const float* __restrict__ Wf,
    float* __restrict__ outp) {
  __shared__ float mean[16][DH_];
  const int row0 = blockIdx.x * 16;
  const int tid = threadIdx.x;
#pragma unroll
  for (int i = 0; i < 4; ++i) {
    int idx = tid + i * 256;
    int r = idx >> 6, e = idx & 63;
    int gs = row0 + r;
    int bb = gs >> 11, ss = gs & (S_ - 1);
    float acc = 0.f;
#pragma unroll
    for (int hh = 0; hh < H_; ++hh)
      acc += heads[(((size_t)bb * H_ + hh) * S_ + ss) * DH_ + e];
    mean[r][e] = acc * 0.25f;
  }
  __syncthreads();
  float acc[16];
#pragma unroll
  for (int r = 0; r < 16; ++r) acc[r] = 0.f;
  for (int e = 0; e < DH_; ++e) {
    float wf = Wf[(size_t)e * D_ + tid];
#pragma unroll
    for (int r = 0; r < 16; ++r) acc[r] += mean[r][e] * wf;
  }
#pragma unroll
  for (int r = 0; r < 16; ++r)
    outp[(size_t)(row0 + r) * D_ + tid] = acc[r];
}

extern "C" void kernel_launch(void* const* d_in, const int* in_sizes, int n_in,
                              void* d_out, int out_size, void* d_ws, size_t ws_size,
                              hipStream_t stream) {
  (void)in_sizes; (void)n_in; (void)out_size; (void)ws_size;
  const float* q  = (const float*)d_in[0];
  const float* k  = (const float*)d_in[1];
  const float* v  = (const float*)d_in[2];
  const unsigned char* mask = (const unsigned char*)d_in[3];
  const float* Wq = (const float*)d_in[4];
  const float* bq = (const float*)d_in[5];
  const float* Wk = (const float*)d_in[6];
  const float* bk = (const float*)d_in[7];
  const float* Wv = (const float*)d_in[8];
  const float* bv = (const float*)d_in[9];
  const float* Wf = (const float*)d_in[10];

  float* out  = (float*)d_out;
  float* attn = out + (size_t)B_ * S_ * D_;

  char* ws = (char*)d_ws;
  short* qh    = (short*)(ws);
  short* kh    = (short*)(ws + 4194304);
  short* vT    = (short*)(ws + 8388608);
  short* WqT   = (short*)(ws + 9437184);
  short* WkT   = (short*)(ws + 9568256);
  short* WvT   = (short*)(ws + 9699328);
  float* heads = (float*)(ws + 9732096);
  int*   flag  = (int*)(ws + 18120704);
  uint*  mbits = (uint*)(ws + 18120768);  // 2 MB bit-packed mask

  detect_kernel<<<1, 256, 0, stream>>>((const unsigned int*)mask, flag);
  prep_pack<<<2368, 256, 0, stream>>>(mask, flag, mbits, Wq, Wk, Wv, WqT, WkT, WvT);
  proj_all<<<dim3(32, 9, B_), 256, 0, stream>>>(q, k, v, WqT, WkT, WvT, bq, bk, bv, qh, kh, vT);
  attn_kernel<<<512, 512, 0, stream>>>(qh, kh, vT, mbits, attn, heads);
  final_kernel<<<512, 256, 0, stream>>>(heads, Wf, out);
}

// Round 16
// 163.639 us; speedup vs baseline: 1.0533x; 1.0533x over previous
//
#include <hip/hip_runtime.h>
#include <stdint.h>
#include <stddef.h>

#define B_ 4
#define S_ 2048
#define D_ 256
#define H_ 4
#define DH_ 64
#define NTT 64
#define SC_LOG2E 0.18033688011112042f  // (1/8) * log2(e)

typedef __attribute__((ext_vector_type(8))) short short8;
typedef __attribute__((ext_vector_type(4))) short short4v;
typedef __attribute__((ext_vector_type(4))) float f32x4;
typedef unsigned int uint;

__device__ __forceinline__ short bf16_rne(float f) {
  union { float f; uint32_t u; } c; c.f = f;
  uint32_t u = c.u + 0x7FFFu + ((c.u >> 16) & 1u);
  return (short)(u >> 16);
}

__device__ __forceinline__ f32x4 mfma16(short8 a, short8 b, f32x4 c) {
  return __builtin_amdgcn_mfma_f32_16x16x32_bf16(a, b, c, 0, 0, 0);
}

__device__ __forceinline__ void gl_lds16(const short* g, short* l) {
  __builtin_amdgcn_global_load_lds(
      (const __attribute__((address_space(1))) unsigned int*)g,
      (__attribute__((address_space(3))) unsigned int*)l, 16, 0, 0);
}

// ---------------- kernel A: weight prep (wgs 0..319) + mask dtype detect (wg 320) ----------------
__global__ __launch_bounds__(256) void prep_detect(
    const float* __restrict__ Wq, const float* __restrict__ Wk, const float* __restrict__ Wv,
    short* __restrict__ WqT, short* __restrict__ WkT, short* __restrict__ WvT,
    const unsigned int* __restrict__ m, int* __restrict__ flag) {
  const int bx = blockIdx.x;
  if (bx < 320) {
    int tid = bx * 256 + threadIdx.x;  // 0..81919
    if (tid < 65536) {
      int n = tid >> 8, d = tid & 255;
      int hh = n >> 6, e = n & 63;
      WqT[tid] = bf16_rne(Wq[((size_t)hh * D_ + d) * DH_ + e] * SC_LOG2E);
      WkT[tid] = bf16_rne(Wk[((size_t)hh * D_ + d) * DH_ + e]);
    } else {
      int t2 = tid - 65536;
      int e = t2 >> 8, d = t2 & 255;
      WvT[t2] = bf16_rne(Wv[(size_t)d * DH_ + e]);
    }
  } else {
    __shared__ int isbool;
    if (threadIdx.x == 0) isbool = 0;
    __syncthreads();
#pragma unroll
    for (int i = 0; i < 4; ++i) {
      unsigned int d = m[threadIdx.x + i * 256];
      if (d & 0xFFFFFFFEu) isbool = 1;
    }
    __syncthreads();
    if (threadIdx.x == 0) *flag = isbool ? 0 : 1;
  }
}

// ---------------- kernel B: bit-pack mask (wgs 0..2047) + projections (wgs 2048..3199) ----------------
__global__ __launch_bounds__(256) void pack_proj(
    const unsigned char* __restrict__ maskB, const int* __restrict__ flagp,
    uint* __restrict__ mbits,
    const float* __restrict__ q, const float* __restrict__ k, const float* __restrict__ v,
    const short* __restrict__ WqT, const short* __restrict__ WkT, const short* __restrict__ WvT,
    const float* __restrict__ bq, const float* __restrict__ bk, const float* __restrict__ bv,
    short* __restrict__ qh, short* __restrict__ kh, short* __restrict__ vT) {
  const int bx = blockIdx.x;
  if (bx < 2048) {
    int tid = bx * 256 + threadIdx.x;  // 524288 dwords total
    uint w = 0;
    if (*flagp) {  // int32 mask
      const uint4* p = (const uint4*)((const uint*)maskB + (size_t)tid * 32);
#pragma unroll
      for (int i = 0; i < 8; ++i) {
        uint4 d = p[i];
        w |= (d.x ? 1u : 0u) << (i * 4);
        w |= (d.y ? 1u : 0u) << (i * 4 + 1);
        w |= (d.z ? 1u : 0u) << (i * 4 + 2);
        w |= (d.w ? 1u : 0u) << (i * 4 + 3);
      }
    } else {  // byte mask
      const uint4* p = (const uint4*)(maskB + (size_t)tid * 32);
#pragma unroll
      for (int i = 0; i < 2; ++i) {
        uint4 d = p[i];
        const uint* dw = (const uint*)&d;
#pragma unroll
        for (int j = 0; j < 4; ++j) {
          uint x = dw[j];
          int base = i * 16 + j * 4;
          w |= ((x & 0x000000FFu) ? 1u : 0u) << (base);
          w |= ((x & 0x0000FF00u) ? 1u : 0u) << (base + 1);
          w |= ((x & 0x00FF0000u) ? 1u : 0u) << (base + 2);
          w |= ((x & 0xFF000000u) ? 1u : 0u) << (base + 3);
        }
      }
    }
    mbits[tid] = w;
    return;
  }

  // projection half: wg = bx - 2048 in [0, 1152); decode (s0, yy, b); 1152 = 32*9*4
  const int wg = bx - 2048;
  const int s0 = (wg & 31) * 64;
  const int yy = (wg >> 5) % 9;
  const int b = wg / 288;

  const float* X; const short* WT; const float* bias; short* outp;
  int vmode, n0; float bscale;
  if (yy < 4)      { X = q; WT = WqT; bias = bq; outp = qh; vmode = 0; bscale = SC_LOG2E; n0 = yy * 64; }
  else if (yy < 8) { X = k; WT = WkT; bias = bk; outp = kh; vmode = 0; bscale = 1.0f; n0 = (yy - 4) * 64; }
  else             { X = v; WT = WvT; bias = bv; outp = vT; vmode = 1; bscale = 1.0f; n0 = 0; }

  const int tid = threadIdx.x;
  const int wave = tid >> 6, lane = tid & 63;
  const int lr = lane & 15, lg = lane >> 4;

  const int arowi = s0 + wave * 16 + lr;
  const float* xr = X + ((size_t)b * S_ + arowi) * D_;

  f32x4 zero4 = {0.f, 0.f, 0.f, 0.f};
  f32x4 acc[4];
#pragma unroll
  for (int ct = 0; ct < 4; ++ct) acc[ct] = zero4;

#pragma unroll
  for (int c = 0; c < 8; ++c) {
    const int k0 = c * 32 + lg * 8;
    f32x4 x0 = *(const f32x4*)(xr + k0);
    f32x4 x1 = *(const f32x4*)(xr + k0 + 4);
    short8 a;
#pragma unroll
    for (int jj = 0; jj < 4; ++jj) { a[jj] = bf16_rne(x0[jj]); a[4 + jj] = bf16_rne(x1[jj]); }
#pragma unroll
    for (int ct = 0; ct < 4; ++ct) {
      short8 bw = *(const short8*)(WT + (size_t)(n0 + ct * 16 + lr) * D_ + k0);
      acc[ct] = mfma16(a, bw, acc[ct]);
    }
  }

  if (vmode == 0) {
#pragma unroll
    for (int ct = 0; ct < 4; ++ct) {
      int n = n0 + ct * 16 + lr;
      float bb = bias[n] * bscale;
      int hh = n >> 6, e = n & 63;
#pragma unroll
      for (int r = 0; r < 4; ++r) {
        int srow = s0 + wave * 16 + lg * 4 + r;
        outp[(((size_t)b * H_ + hh) * S_ + srow) * DH_ + e] = bf16_rne(acc[ct][r] + bb);
      }
    }
  } else {
#pragma unroll
    for (int ct = 0; ct < 4; ++ct) {
      int n = n0 + ct * 16 + lr;
      float bb = bias[n];
      int s4 = s0 + wave * 16 + lg * 4;
      short4v pk;
#pragma unroll
      for (int r = 0; r < 4; ++r) pk[r] = bf16_rne(acc[ct][r] + bb);
      *(short4v*)(outp + ((size_t)b * DH_ + n) * S_ + s4) = pk;
    }
  }
}

// ---------------- staging helpers (NTT=64 tiles, inverse-swizzled source) ----------------
__device__ __forceinline__ void stageK64(const short* Ksrc, short* dst, int wq, int lane) {
#pragma unroll
  for (int i = 0; i < 2; ++i) {
    int ub = i * 256 + wq * 64;
    int u = ub + lane;
    int row = u >> 3, c = (u ^ row) & 7;
    gl_lds16(Ksrc + (size_t)row * 64 + c * 8, dst + (size_t)ub * 8);
  }
}

__device__ __forceinline__ void stageV64(const short* Vb, int t0, short* dst, int wq, int lane) {
#pragma unroll
  for (int i = 0; i < 2; ++i) {
    int ub = i * 256 + wq * 64;
    int u = ub + lane;
    int er = u >> 3, c = (u ^ er) & 7;
    gl_lds16(Vb + (size_t)er * S_ + t0 + c * 8, dst + (size_t)ub * 8);
  }
}

// ---------------- fused masked attention (R10-exact: best measured 166.5 us) ----------------
// grid 512 (XCD-swizzled), 512 thr. Waves 0-3: t in [0,1024); waves 4-7: t in [1024,2048).
// Counted-vmcnt staging + setprio; two barriers/tile; plain cached stores.
__global__ __launch_bounds__(512, 4) void attn_kernel(
    const short* __restrict__ qh, const short* __restrict__ kh,
    const short* __restrict__ vT, const uint* __restrict__ mbits,
    float* __restrict__ attn, float* __restrict__ heads) {
  __shared__ __align__(16) short Kt[2][2][4096];  // [half][dbuf] 32 KB
  __shared__ __align__(16) short Vt[2][2][4096];  // [half][dbuf] 32 KB
  __shared__ __align__(16) short Pt[8][1024];     // per-wave P slab, 16 KB (aliased: fsum, ocomb)

  const int flat = blockIdx.x;
  const int xcd = flat & 7;
  const int pos = flat >> 3;              // 0..63
  const int bh_i = xcd * 2 + (pos >> 5);  // 2 (b,h) per XCD
  const int q0 = (pos & 31) * 64;
  const int b = bh_i >> 2, h = bh_i & 3;

  const int tid = threadIdx.x;
  const int wave = tid >> 6, lane = tid & 63;
  const int half = wave >> 2, wq = wave & 3;
  const int lr = lane & 15, lg = lane >> 4;
  const int tbase = half * (S_ / 2);

  const size_t bh = (size_t)b * H_ + h;
  const short* Qb = qh + bh * S_ * DH_;
  const short* Kb = kh + bh * S_ * DH_;
  const short* Vb = vT + (size_t)b * DH_ * S_;

  const int qrow = q0 + wq * 16 + lr;
  const uint* mrow = mbits + ((size_t)b * S_ + qrow) * (S_ / 32);
  float* arow = attn + (bh * S_ + qrow) * S_;

  const short8 aq0 = *(const short8*)(Qb + (size_t)qrow * DH_ + lg * 8);
  const short8 aq1 = *(const short8*)(Qb + (size_t)qrow * DH_ + 32 + lg * 8);

  short* pw = &Pt[wave][0];

  // -------- pass 1: partial row sums over this wave's t-half --------
  float rsum = 0.f;
  stageK64(Kb + (size_t)tbase * DH_, Kt[half][0], wq, lane);
  asm volatile("s_waitcnt vmcnt(0)" ::: "memory");
  __builtin_amdgcn_s_barrier();
  int cur = 0;
  for (int tt = 0; tt < 16; ++tt) {
    const int t0 = tbase + tt * NTT;
    uint2 mv = *(const uint2*)(mrow + (t0 >> 5));
    if (tt + 1 < 16) {
      stageK64(Kb + (size_t)(t0 + NTT) * DH_, Kt[half][cur ^ 1], wq, lane);
      asm volatile("s_waitcnt vmcnt(3)" ::: "memory");  // stage(tt) retired
    } else {
      asm volatile("s_waitcnt vmcnt(1)" ::: "memory");
    }
    __builtin_amdgcn_s_barrier();  // A: tile tt visible to all waves of this half
    __builtin_amdgcn_s_setprio(1);
    const short* kt = Kt[half][cur];
#pragma unroll
    for (int j = 0; j < 4; ++j) {
      int row = j * 16 + lr;
      short8 bk0 = *(const short8*)(kt + row * 64 + (((lg) ^ row) & 7) * 8);
      short8 bk1 = *(const short8*)(kt + row * 64 + (((lg + 4) ^ row) & 7) * 8);
      f32x4 acc = {0.f, 0.f, 0.f, 0.f};
      acc = mfma16(bk0, aq0, acc);
      acc = mfma16(bk1, aq1, acc);
      uint mw = (j < 2) ? mv.x : mv.y;
#pragma unroll
      for (int r = 0; r < 4; ++r) {
        int sh = (j & 1) * 16 + lg * 4 + r;
        float p = ((mw >> sh) & 1u) ? 0.f : __builtin_exp2f(acc[r]);
        rsum += p;
      }
    }
    __builtin_amdgcn_s_setprio(0);
    __builtin_amdgcn_s_barrier();  // B: done reading buf[cur] before next stage overwrite
    cur ^= 1;
  }
  rsum += __shfl_xor(rsum, 16);
  rsum += __shfl_xor(rsum, 32);
  // combine the two t-halves through LDS (fsum aliased onto Pt)
  float* fsum = (float*)&Pt[0][0];  // [8][16]
  if (lane < 16) fsum[wave * 16 + lr] = rsum;
  __syncthreads();
  const float rinv = 1.0f / (fsum[wq * 16 + lr] + fsum[(wq + 4) * 16 + lr]);

  // -------- pass 2: recompute, write attn (float4), PV partials --------
  f32x4 o[4];
#pragma unroll
  for (int ct = 0; ct < 4; ++ct) o[ct] = (f32x4){0.f, 0.f, 0.f, 0.f};

  stageK64(Kb + (size_t)tbase * DH_, Kt[half][0], wq, lane);
  stageV64(Vb, tbase, Vt[half][0], wq, lane);
  asm volatile("s_waitcnt vmcnt(0)" ::: "memory");
  __syncthreads();
  cur = 0;
  for (int tt = 0; tt < 16; ++tt) {
    const int t0 = tbase + tt * NTT;
    uint2 mv = *(const uint2*)(mrow + (t0 >> 5));
    if (tt + 1 < 16) {
      stageK64(Kb + (size_t)(t0 + NTT) * DH_, Kt[half][cur ^ 1], wq, lane);
      stageV64(Vb, t0 + NTT, Vt[half][cur ^ 1], wq, lane);
      asm volatile("s_waitcnt vmcnt(9)" ::: "memory");  // stage(tt) retired; stores fly
    } else {
      asm volatile("s_waitcnt vmcnt(5)" ::: "memory");
    }
    __builtin_amdgcn_s_barrier();  // A
    __builtin_amdgcn_s_setprio(1);
    const short* kt = Kt[half][cur];
    const short* vt = Vt[half][cur];
#pragma unroll
    for (int j = 0; j < 4; ++j) {
      int row = j * 16 + lr;
      short8 bk0 = *(const short8*)(kt + row * 64 + (((lg) ^ row) & 7) * 8);
      short8 bk1 = *(const short8*)(kt + row * 64 + (((lg + 4) ^ row) & 7) * 8);
      f32x4 acc = {0.f, 0.f, 0.f, 0.f};
      acc = mfma16(bk0, aq0, acc);
      acc = mfma16(bk1, aq1, acc);
      uint mw = (j < 2) ? mv.x : mv.y;
      f32x4 pst;
      short4v pk;
#pragma unroll
      for (int r = 0; r < 4; ++r) {
        int sh = (j & 1) * 16 + lg * 4 + r;
        float p = ((mw >> sh) & 1u) ? 0.f : __builtin_exp2f(acc[r]) * rinv;
        pst[r] = p;
        pk[r] = bf16_rne(p);
      }
      *(f32x4*)(arow + t0 + j * 16 + lg * 4) = pst;
      *(short4v*)(pw + lr * 64 + (((2 * j + (lg >> 1)) ^ lr) & 7) * 8 + (lg & 1) * 4) = pk;
    }
    // PV: o[e][q] += V^T[e][t] * P[q][t]; apf is ct-invariant -> hoisted
    short8 apf[2];
#pragma unroll
    for (int kc = 0; kc < 2; ++kc)
      apf[kc] = *(const short8*)(pw + lr * 64 + (((4 * kc + lg) ^ lr) & 7) * 8);
#pragma unroll
    for (int ct = 0; ct < 4; ++ct) {
      int er = ct * 16 + lr;
#pragma unroll
      for (int kc = 0; kc < 2; ++kc) {
        short8 bvf = *(const short8*)(vt + er * 64 + (((4 * kc + lg) ^ er) & 7) * 8);
        o[ct] = mfma16(bvf, apf[kc], o[ct]);
      }
    }
    __builtin_amdgcn_s_setprio(0);
    __builtin_amdgcn_s_barrier();  // B
    cur ^= 1;
  }

  // -------- combine o partials across the two t-halves (ocomb aliased onto Pt) --------
  float* ocomb = (float*)&Pt[0][0];  // [4][16][64] floats = 16 KB
  if (half == 1) {
#pragma unroll
    for (int ct = 0; ct < 4; ++ct)
      *(f32x4*)(ocomb + wq * 1024 + lr * 64 + ct * 16 + lg * 4) = o[ct];
  }
  __syncthreads();
  if (half == 0) {
#pragma unroll
    for (int ct = 0; ct < 4; ++ct) {
      f32x4 t = *(const f32x4*)(ocomb + wq * 1024 + lr * 64 + ct * 16 + lg * 4);
      f32x4 s = o[ct];
      s[0] += t[0]; s[1] += t[1]; s[2] += t[2]; s[3] += t[3];
      *(f32x4*)(heads + (bh * S_ + qrow) * DH_ + ct * 16 + lg * 4) = s;
    }
  }
}

// ---------------- mean over heads + final projection ----------------
__global__ __launch_bounds__(256) void final_kernel(
    const float* __restrict__ heads, const float* __restrict__ Wf,
    float* __restrict__ outp) {
  __shared__ float mean[16][DH_];
  const int row0 = blockIdx.x * 16;
  const int tid = threadIdx.x;
#pragma unroll
  for (int i = 0; i < 4; ++i) {
    int idx = tid + i * 256;
    int r = idx >> 6, e = idx & 63;
    int gs = row0 + r;
    int bb = gs >> 11, ss = gs & (S_ - 1);
    float acc = 0.f;
#pragma unroll
    for (int hh = 0; hh < H_; ++hh)
      acc += heads[(((size_t)bb * H_ + hh) * S_ + ss) * DH_ + e];
    mean[r][e] = acc * 0.25f;
  }
  __syncthreads();
  float acc[16];
#pragma unroll
  for (int r = 0; r < 16; ++r) acc[r] = 0.f;
  for (int e = 0; e < DH_; ++e) {
    float wf = Wf[(size_t)e * D_ + tid];
#pragma unroll
    for (int r = 0; r < 16; ++r) acc[r] += mean[r][e] * wf;
  }
#pragma unroll
  for (int r = 0; r < 16; ++r)
    outp[(size_t)(row0 + r) * D_ + tid] = acc[r];
}

extern "C" void kernel_launch(void* const* d_in, const int* in_sizes, int n_in,
                              void* d_out, int out_size, void* d_ws, size_t ws_size,
                              hipStream_t stream) {
  (void)in_sizes; (void)n_in; (void)out_size; (void)ws_size;
  const float* q  = (const float*)d_in[0];
  const float* k  = (const float*)d_in[1];
  const float* v  = (const float*)d_in[2];
  const unsigned char* mask = (const unsigned char*)d_in[3];
  const float* Wq = (const float*)d_in[4];
  const float* bq = (const float*)d_in[5];
  const float* Wk = (const float*)d_in[6];
  const float* bk = (const float*)d_in[7];
  const float* Wv = (const float*)d_in[8];
  const float* bv = (const float*)d_in[9];
  const float* Wf = (const float*)d_in[10];

  float* out  = (float*)d_out;
  float* attn = out + (size_t)B_ * S_ * D_;

  char* ws = (char*)d_ws;
  short* qh    = (short*)(ws);
  short* kh    = (short*)(ws + 4194304);
  short* vT    = (short*)(ws + 8388608);
  short* WqT   = (short*)(ws + 9437184);
  short* WkT   = (short*)(ws + 9568256);
  short* WvT   = (short*)(ws + 9699328);
  float* heads = (float*)(ws + 9732096);
  int*   flag  = (int*)(ws + 18120704);
  uint*  mbits = (uint*)(ws + 18120768);  // 2 MB bit-packed mask

  prep_detect<<<321, 256, 0, stream>>>(Wq, Wk, Wv, WqT, WkT, WvT,
                                       (const unsigned int*)mask, flag);
  pack_proj<<<3200, 256, 0, stream>>>(mask, flag, mbits,
                                      q, k, v, WqT, WkT, WvT, bq, bk, bv, qh, kh, vT);
  attn_kernel<<<512, 512, 0, stream>>>(qh, kh, vT, mbits, attn, heads);
  final_kernel<<<512, 256, 0, stream>>>(heads, Wf, out);
}